// Round 9
// baseline (57.260 us; speedup 1.0000x reference)
//
#include <hip/hip_runtime.h>

// CurvatureLoss: pred (8,4,1024,1024) fp32 -> scalar loss. target unused.
// C=2 cols/lane register-ring sweep, RCHUNK=16, rings {P:4, L:5, Rr:4}, 20
// steps fully unrolled. Lap+curvature math forced to packed fp32 via inline
// asm v_pk_{add,mul,fma}_f32 (LLVM scalarizes generic <2 x float>). Softmax
// e0-normalized (6 exps/step). DPP cross-lane. Masks hoisted to epilogue.

namespace {
constexpr int H = 1024, W = 1024, B = 8;
constexpr int VALID = 120;            // output cols per wave (64 lanes x 2 - 8)
constexpr int NSTRIPS = 9;            // 9 * 120 = 1080 >= 1024
constexpr int RCHUNK = 16;            // output rows per wave
constexpr int NCHUNKS = H / RCHUNK;   // 64
constexpr int WPB = 4;                // waves per block
constexpr int NTHREADS = 64 * WPB;
constexpr size_t HW = (size_t)H * W;
}

using v2f = __attribute__((ext_vector_type(2))) float;

__device__ __forceinline__ v2f mk2(float a, float b) {
    v2f r; r.x = a; r.y = b; return r;
}

// ---- forced packed fp32 (VOP3P) ----
__device__ __forceinline__ v2f pk_add(v2f a, v2f b) {
    v2f d; asm("v_pk_add_f32 %0, %1, %2" : "=v"(d) : "v"(a), "v"(b)); return d;
}
__device__ __forceinline__ v2f pk_sub(v2f a, v2f b) {   // a - b
    v2f d; asm("v_pk_add_f32 %0, %1, %2 neg_lo:[0,1] neg_hi:[0,1]"
               : "=v"(d) : "v"(a), "v"(b)); return d;
}
__device__ __forceinline__ v2f pk_mul(v2f a, v2f b) {
    v2f d; asm("v_pk_mul_f32 %0, %1, %2" : "=v"(d) : "v"(a), "v"(b)); return d;
}
__device__ __forceinline__ v2f pk_fma(v2f a, v2f b, v2f c) {   // a*b + c
    v2f d; asm("v_pk_fma_f32 %0, %1, %2, %3"
               : "=v"(d) : "v"(a), "v"(b), "v"(c)); return d;
}
__device__ __forceinline__ v2f pk_fms(v2f a, v2f b, v2f c) {   // a*b - c
    v2f d; asm("v_pk_fma_f32 %0, %1, %2, %3 neg_lo:[0,0,1] neg_hi:[0,0,1]"
               : "=v"(d) : "v"(a), "v"(b), "v"(c)); return d;
}

// DPP cross-lane: neighbor lane's value. Out-of-range lane -> 0 (unused lanes).
__device__ __forceinline__ float dpp_left(float x) {   // lane n <- lane n-1
    return __builtin_bit_cast(float,
        __builtin_amdgcn_update_dpp(0, __builtin_bit_cast(int, x),
                                    0x138 /*wave_shr1*/, 0xf, 0xf, false));
}
__device__ __forceinline__ float dpp_right(float x) {  // lane n <- lane n+1
    return __builtin_bit_cast(float,
        __builtin_amdgcn_update_dpp(0, __builtin_bit_cast(int, x),
                                    0x130 /*wave_shl1*/, 0xf, 0xf, false));
}

// ws layout: float s[24] | unsigned c[24]  (8 batches x 3 fields)
__global__ void zero_ws_kernel(unsigned int* ws) {
    if (threadIdx.x < 48) ws[threadIdx.x] = 0u;
}

template <bool RE>
__device__ __forceinline__ void load_row4(const float* __restrict__ basep, int row,
                                          v2f o[4]) {
    const int rc = RE ? min(max(row, 0), H - 1) : row;  // masked later
    const float* p = basep + (size_t)rc * W;
    o[0] = *(const v2f*)p;
    o[1] = *(const v2f*)(p + HW);
    o[2] = *(const v2f*)(p + 2 * HW);
    o[3] = *(const v2f*)(p + 3 * HW);
}

// e0-normalized softmax over 4 channels for 2 columns (ratios identical to
// softmax; inputs ~N(0,1) so exp(|d|<~12) is safe). p = {p1, p1+p2, p3}.
template <bool EDGE>
__device__ __forceinline__ void softmax_pair(const v2f x[4], bool ok0, bool ok1,
                                             v2f p[3]) {
    const v2f d1 = pk_sub(x[1], x[0]);
    const v2f d2 = pk_sub(x[2], x[0]);
    const v2f d3 = pk_sub(x[3], x[0]);
    const float e1x = __expf(d1.x), e1y = __expf(d1.y);
    const float e2x = __expf(d2.x), e2y = __expf(d2.y);
    const float e3x = __expf(d3.x), e3y = __expf(d3.y);
    const float t12x = e1x + e2x,   t12y = e1y + e2y;
    const float Sx = 1.f + (t12x + e3x), Sy = 1.f + (t12y + e3y);
    const float ix = __builtin_amdgcn_rcpf(Sx);
    const float iy = __builtin_amdgcn_rcpf(Sy);
    if (EDGE) {
        p[0] = mk2(ok0 ? e1x * ix : 0.f,   ok1 ? e1y * iy : 0.f);
        p[1] = mk2(ok0 ? t12x * ix : 0.f,  ok1 ? t12y * iy : 0.f);
        p[2] = mk2(ok0 ? e3x * ix : 0.f,   ok1 ? e3y * iy : 0.f);
    } else {
        p[0] = mk2(e1x * ix,   e1y * iy);
        p[1] = mk2(t12x * ix,  t12y * iy);
        p[2] = mk2(e3x * ix,   e3y * iy);
    }
}

template <bool CE, bool RE>
__device__ __forceinline__ void sweep(const float* __restrict__ pred,
                                      int b, int strip, int chunk, int lane,
                                      v2f sacc[3], unsigned int cacc0[3],
                                      unsigned int cacc1[3]) {
    const int r0 = chunk * RCHUNK;
    const int li0 = 2 * lane;            // local col index 0..127
    const int col0 = strip * VALID - 4 + li0;
    const int col1 = col0 + 1;
    const int colC = CE ? min(max(col0, 0), W - 2) : col0;  // even -> 8B aligned
    const float* basep = pred + (size_t)b * 4 * HW + colC;

    const bool cOK0 = !CE || ((unsigned)col0 < (unsigned)W);
    const bool cOK1 = !CE || ((unsigned)col1 < (unsigned)W);
    // gx +-1 shift pad masks (CE only; interior folds to 1)
    const float gxpM0 = (!CE || (col0 + 1 < W)) ? 1.f : 0.f;
    const float gxpM1 = (!CE || (col1 + 1 < W)) ? 1.f : 0.f;
    const float gxmM0 = (!CE || (col0 >= 1)) ? 1.f : 0.f;
    const float gxmM1 = (!CE || (col1 >= 1)) ? 1.f : 0.f;

    const v2f ONE   = mk2(1.f, 1.f);
    const v2f TWO   = mk2(2.f, 2.f);
    const v2f NTWO  = mk2(-2.f, -2.f);
    const v2f NFOUR = mk2(-4.f, -4.f);

    v2f P[4][3];   // prob ring [slot = i%4][field]
    v2f L[5][3];   // lap ring  [slot = i%5][field]
    v2f Rr[4][4];  // raw ring  [slot = i%4][channel], prefetch depth 4 steps

    // Prologue: P[2] = prob(r0-3), P[3] = prob(r0-2);
    //           Rr[0..3] = raw rows r0-1 .. r0+2.
    {
        v2f t[4];
        load_row4<RE>(basep, r0 - 3, t);
        const bool ok = !RE || ((unsigned)(r0 - 3) < (unsigned)H);
        softmax_pair<CE || RE>(t, ok && cOK0, ok && cOK1, P[2]);
        load_row4<RE>(basep, r0 - 2, t);
        const bool ok2 = !RE || ((unsigned)(r0 - 2) < (unsigned)H);
        softmax_pair<CE || RE>(t, ok2 && cOK0, ok2 && cOK1, P[3]);
    }
    load_row4<RE>(basep, r0 - 1, Rr[0]);
    load_row4<RE>(basep, r0 + 0, Rr[1]);
    load_row4<RE>(basep, r0 + 1, Rr[2]);
    load_row4<RE>(basep, r0 + 2, Rr[3]);

#pragma unroll
    for (int i = 0; i < RCHUNK + 4; ++i) {        // 20 steps, fully unrolled
        const int y = r0 - 4 + i;                  // output row of this step
        // 1) prob row y+3 from Rr[i%4] -> P[i%4]
        const bool pok = !RE || ((unsigned)(y + 3) < (unsigned)H);
        softmax_pair<CE || RE>(Rr[i % 4], pok && cOK0, pok && cOK1, P[i % 4]);
        // 2) prefetch raw row y+7 -> Rr[i%4] (consumed at step i+4)
        if (i < RCHUNK) load_row4<RE>(basep, y + 7, Rr[i % 4]);
        // 3) lap row y+2 -> L[i%5] from prob rows y+1, y+2, y+3
        const bool lok = !RE || ((unsigned)(y + 2) < (unsigned)H);
#pragma unroll
        for (int f = 0; f < 3; ++f) {
            const v2f top = P[(i + 2) % 4][f];
            const v2f mid = P[(i + 3) % 4][f];
            const v2f bot = P[i % 4][f];
            const v2f vsum = pk_add(top, bot);
            v2f hsum;
            hsum.x = dpp_left(mid.y) + mid.y;     // left(col0) + right(col0)
            hsum.y = mid.x + dpp_right(mid.x);    // left(col1) + right(col1)
            v2f l = pk_fma(mid, NFOUR, pk_add(vsum, hsum));
            if (CE || RE) {
                l.x = (lok && cOK0) ? l.x : 0.f;
                l.y = (lok && cOK1) ? l.y : 0.f;
            }
            L[i % 5][f] = l;
        }
        // 4) output row y from lap rows y-2..y+2 (first 4 steps: prologue)
        if (i >= 4) {
            const float gypM = (!RE || (y + 1 < H)) ? 1.f : 0.f;
            const float gymM = (!RE || (y >= 1)) ? 1.f : 0.f;
#pragma unroll
            for (int f = 0; f < 3; ++f) {
                const v2f lm2 = L[(i + 1) % 5][f];
                const v2f lm1 = L[(i + 2) % 5][f];
                const v2f lc  = L[(i + 3) % 5][f];
                const v2f lp1 = L[(i + 4) % 5][f];
                const v2f lp2 = L[i % 5][f];
                const float A  = dpp_left(lc.y);   // lap(li0-1)
                const float Bm = dpp_left(lc.x);   // lap(li0-2)
                const float Bp = dpp_right(lc.x);  // lap(li0+2)
                const float Cc = dpp_right(lc.y);  // lap(li0+3)
                // gx per col; identities: gxp.x == gx.y, gxm.y == gx.x
                v2f gx;  gx.x = lc.y - A;  gx.y = Bp - lc.x;
                float gxpx = gx.y, gxpy = Cc - lc.y;
                float gxmx = lc.x - Bm, gxmy = gx.x;
                if (CE) {
                    gxpx *= gxpM0; gxpy *= gxpM1;
                    gxmx *= gxmM0; gxmy *= gxmM1;
                }
                const v2f gxp = mk2(gxpx, gxpy);
                const v2f gxm = mk2(gxmx, gxmy);
                const v2f gy = pk_sub(lp1, lm1);
                v2f gyp = pk_sub(lp2, lc);
                v2f gym = pk_sub(lc, lm2);
                if (RE) {
                    gyp.x *= gypM; gyp.y *= gypM;
                    gym.x *= gymM; gym.y *= gymM;
                }
                const v2f hxx = pk_fms(gx, TWO, pk_add(gxp, gxm));
                const v2f hxy = pk_sub(gxp, gxm);
                const v2f hyy = pk_fms(gy, TWO, pk_add(gyp, gym));
                const v2f ox = pk_add(gx, ONE);
                const v2f oy = pk_add(gy, ONE);
                const v2f n1 = pk_mul(hxx, pk_mul(oy, oy));
                const v2f n2 = pk_fma(hyy, pk_mul(ox, ox), n1);
                const v2f ht = pk_mul(hxy, pk_mul(gx, gy));
                const v2f numer = pk_fma(ht, NTWO, n2);
                v2f xx = pk_fma(gx, gx, ONE);
                xx = pk_fma(gy, gy, xx);
                const v2f xx3 = pk_mul(pk_mul(xx, xx), xx);
                const float rs0 = __builtin_amdgcn_rsqf(xx3.x);  // xx^-1.5
                const float rs1 = __builtin_amdgcn_rsqf(xx3.y);
                // 2x true curvature; 0.5 folded into the epilogue.
                const float c2x = numer.x * rs0;
                const float c2y = numer.y * rs1;
                const float ngx = fmaxf(-c2x, 0.f);
                const float ngy = fmaxf(-c2y, 0.f);
                sacc[f].x += ngx;
                sacc[f].y += ngy;
                cacc0[f] += (ngx != 0.f) ? 1u : 0u;
                cacc1[f] += (ngy != 0.f) ? 1u : 0u;
            }
        }
    }
}

__global__ __launch_bounds__(NTHREADS, 4)
void curvature_sweep(const float* __restrict__ pred,
                     float* __restrict__ s_ws,
                     unsigned int* __restrict__ c_ws) {
    __shared__ float redS[3][WPB];
    __shared__ unsigned int redC[3][WPB];

    const int strip = blockIdx.x;
    const int b = blockIdx.z;
    const int tid = threadIdx.x;
    const int wv = tid >> 6, lane = tid & 63;
    const int chunk = blockIdx.y * WPB + wv;

    const bool ce = (strip == 0) || (strip == NSTRIPS - 1);
    const bool re = (chunk == 0) || (chunk == NCHUNKS - 1);

    v2f sacc[3] = {mk2(0.f, 0.f), mk2(0.f, 0.f), mk2(0.f, 0.f)};
    unsigned int cacc0[3] = {0u, 0u, 0u};
    unsigned int cacc1[3] = {0u, 0u, 0u};
    if (!ce && !re)
        sweep<false, false>(pred, b, strip, chunk, lane, sacc, cacc0, cacc1);
    else if (ce && !re)
        sweep<true, false>(pred, b, strip, chunk, lane, sacc, cacc0, cacc1);
    else if (!ce && re)
        sweep<false, true>(pred, b, strip, chunk, lane, sacc, cacc0, cacc1);
    else
        sweep<true, true>(pred, b, strip, chunk, lane, sacc, cacc0, cacc1);

    // Epilogue masking (hoisted): valid lanes are 2..61 (local cols 4..123)
    // with in-image columns; validity is lane-uniform across the trip.
    const int col0 = strip * VALID - 4 + 2 * lane;
    const bool gOK = (lane >= 2) && (lane <= 61) && (col0 < W);

    // Wave reduction -> LDS -> one atomic pair per (block, field).
#pragma unroll
    for (int f = 0; f < 3; ++f) {
        float v = gOK ? 0.5f * (sacc[f].x + sacc[f].y) : 0.f;  // 0.5: denom fold
        unsigned int c = gOK ? (cacc0[f] + cacc1[f]) : 0u;
        for (int off = 32; off > 0; off >>= 1) {
            v += __shfl_xor(v, off, 64);
            c += __shfl_xor(c, off, 64);
        }
        if (lane == 0) { redS[f][wv] = v; redC[f][wv] = c; }
    }
    __syncthreads();
    if (tid < 3) {
        float v = 0.f;
        unsigned int c = 0;
        for (int w2 = 0; w2 < WPB; ++w2) { v += redS[tid][w2]; c += redC[tid][w2]; }
        atomicAdd(&s_ws[b * 3 + tid], v);
        atomicAdd(&c_ws[b * 3 + tid], c);
    }
}

__global__ void finalize_kernel(const float* __restrict__ s_ws,
                                const unsigned int* __restrict__ c_ws,
                                float* __restrict__ out) {
    const int lane = threadIdx.x;
    float v = 0.f;
    if (lane < 24) {
        const float s = s_ws[lane];
        const unsigned int c = c_ws[lane];
        v = (c > 0) ? s / (float)c : 0.f;  // max(c,1)==c when c>0
    }
    for (int off = 32; off > 0; off >>= 1) v += __shfl_down(v, off, 64);
    if (lane == 0) out[0] = v;
}

extern "C" void kernel_launch(void* const* d_in, const int* in_sizes, int n_in,
                              void* d_out, int out_size, void* d_ws, size_t ws_size,
                              hipStream_t stream) {
    const float* pred = (const float*)d_in[0];
    float* s_ws = (float*)d_ws;
    unsigned int* c_ws = (unsigned int*)((char*)d_ws + 24 * sizeof(float));
    float* out = (float*)d_out;

    hipLaunchKernelGGL(zero_ws_kernel, dim3(1), dim3(64), 0, stream,
                       (unsigned int*)d_ws);
    dim3 grid(NSTRIPS, NCHUNKS / WPB, B);
    hipLaunchKernelGGL(curvature_sweep, grid, dim3(NTHREADS), 0, stream,
                       pred, s_ws, c_ws);
    hipLaunchKernelGGL(finalize_kernel, dim3(1), dim3(64), 0, stream,
                       s_ws, c_ws, out);
}